// Round 9
// baseline (42.471 us; speedup 1.0000x reference)
//
#include <hip/hip_runtime.h>

#define Bb 16
#define Ll 2048
#define Ee 256
#define E4 64
#define BPB 32          // P1 blocks per batch (64 rows each)
#define RPB 64
#define CBP 16          // kMain blocks per batch (128 rows each)
#define CRP 128

// ws layout (floats). kPrep writes ALL P1 slots (zeros when inactive) so
// kMain's reduce is fixed-count; M/bqk/kvec/beta fully written by kPrep;
// out zeroed by kPrep (ordered before kMain by dispatch).
#define P1_OFF 0                        // [16][32][256] row-sum partials
#define M_OFF  (P1_OFF + Bb*BPB*Ee)     // [256][256] M = Wq^T Wk
#define BQK_OFF (M_OFF + Ee*Ee)         // [256] bqk = bq @ Wk
#define KV_OFF  (BQK_OFF + Ee)          // [256] kvec = Wq^T bk
#define BETA_OFF (KV_OFF + Ee)          // [1]   beta = bq.bk

// kPrep: blocks [0,512): P1 partials (fixed 16-iter masked; zeros if inactive);
//        i==0 zeroes out[b,:].
//        blocks [512,768): row ep of M = Wq^T Wk; kvec[ep]; ep==0: bqk, beta.
__global__ void __launch_bounds__(256) kPrep(const float* __restrict__ x,
                                             const int* __restrict__ lengths,
                                             const float* __restrict__ Wq,
                                             const float* __restrict__ bq,
                                             const float* __restrict__ Wk,
                                             const float* __restrict__ bk,
                                             float* __restrict__ ws,
                                             float* __restrict__ out) {
    const int blk = blockIdx.x;
    const int tid = threadIdx.x, lane = tid & 63, wid = tid >> 6;

    if (blk < Bb * BPB) {
        // ---- P1 role ----
        const int b = blk >> 5, i = blk & 31;
        if (i == 0) out[b * Ee + tid] = 0.f;
        const int len = lengths[b];
        const int r0 = i * RPB;
        float4* slot = (float4*)(ws + P1_OFF + ((size_t)(b * BPB + i)) * Ee);
        if (r0 >= len) {
            if (tid < 64) slot[tid] = make_float4(0.f, 0.f, 0.f, 0.f);
            return;
        }
        const float4* xb = (const float4*)(x + (size_t)b * Ll * Ee);
        float4 acc = {0.f, 0.f, 0.f, 0.f};
#pragma unroll
        for (int rr = 0; rr < 16; ++rr) {
            const int r = r0 + wid + rr * 4;
            float4 v = xb[(size_t)r * E4 + lane];      // padded rows valid memory
            const bool ok = (r < len);
            acc.x += ok ? v.x : 0.f; acc.y += ok ? v.y : 0.f;
            acc.z += ok ? v.z : 0.f; acc.w += ok ? v.w : 0.f;
        }
        __shared__ float4 part[256];
        part[tid] = acc;
        __syncthreads();
        if (tid < 64) {
            float4 a = part[tid], b1 = part[64+tid], c1 = part[128+tid], d1 = part[192+tid];
            slot[tid] = make_float4(a.x+b1.x+c1.x+d1.x, a.y+b1.y+c1.y+d1.y,
                                    a.z+b1.z+c1.z+d1.z, a.w+b1.w+c1.w+d1.w);
        }
        return;
    }

    // ---- M role: row ep ----
    const int ep = blk - Bb * BPB;
    const float4* wk4 = (const float4*)Wk;
    float4 macc = {0.f, 0.f, 0.f, 0.f};
    float4 qacc = {0.f, 0.f, 0.f, 0.f};
    const bool doBqk = (ep == 0);
#pragma unroll 16
    for (int q = 0; q < 64; ++q) {
        const int f = wid * 64 + q;
        const float wq = Wq[(size_t)f * Ee + ep];      // wave-uniform broadcast
        const float4 w4 = wk4[(size_t)f * E4 + lane];
        macc.x += wq * w4.x; macc.y += wq * w4.y;
        macc.z += wq * w4.z; macc.w += wq * w4.w;
        if (doBqk) {
            const float bqf = bq[f];
            qacc.x += bqf * w4.x; qacc.y += bqf * w4.y;
            qacc.z += bqf * w4.z; qacc.w += bqf * w4.w;
        }
    }
    float kv = Wq[(size_t)(wid * 64 + lane) * Ee + ep] * bk[wid * 64 + lane];
#pragma unroll
    for (int m = 32; m; m >>= 1) kv += __shfl_xor(kv, m, 64);

    __shared__ float4 mred[4][64];
    __shared__ float4 qred[4][64];
    __shared__ float kred[4];
    mred[wid][lane] = macc;
    if (doBqk) qred[wid][lane] = qacc;
    if (lane == 0) kred[wid] = kv;
    __syncthreads();
    if (wid == 0) {
        float4 a = mred[0][lane], b1 = mred[1][lane], c1 = mred[2][lane], d1 = mred[3][lane];
        ((float4*)(ws + M_OFF + (size_t)ep * Ee))[lane] =
            make_float4(a.x+b1.x+c1.x+d1.x, a.y+b1.y+c1.y+d1.y,
                        a.z+b1.z+c1.z+d1.z, a.w+b1.w+c1.w+d1.w);
        if (lane == 0) ws[KV_OFF + ep] = kred[0] + kred[1] + kred[2] + kred[3];
    }
    if (doBqk) {
        if (wid == 1) {
            float4 a = qred[0][lane], b1 = qred[1][lane], c1 = qred[2][lane], d1 = qred[3][lane];
            ((float4*)(ws + BQK_OFF))[lane] =
                make_float4(a.x+b1.x+c1.x+d1.x, a.y+b1.y+c1.y+d1.y,
                            a.z+b1.z+c1.z+d1.z, a.w+b1.w+c1.w+d1.w);
        }
        float p = bq[tid] * bk[tid];
#pragma unroll
        for (int m = 32; m; m >>= 1) p += __shfl_xor(p, m, 64);
        __shared__ float bred[4];
        if (lane == 0) bred[wid] = p;
        __syncthreads();
        if (tid == 0) ws[BETA_OFF] = bred[0] + bred[1] + bred[2] + bred[3];
    }
}

// kMain: block (b,i): fixed-32 P1 reduce -> xs; t = xs@M + len*bqk (fixed 64,
// wave-split over ep); c = xs.kvec + len*beta; fixed-32 masked stream over
// 128 rows; block-reduce u,w; fixed-64 Wv projection; atomicAdd into out.
__global__ void __launch_bounds__(256) kMain(const float* __restrict__ x,
                                             const int* __restrict__ lengths,
                                             const float* __restrict__ ws,
                                             const float* __restrict__ Wv,
                                             const float* __restrict__ bv,
                                             float* __restrict__ out) {
    const int b = blockIdx.y, i = blockIdx.x;
    const int len = lengths[b];
    const int r0 = i * CRP;
    if (r0 >= len) return;                  // uniform early-exit, no contribution
    const int tid = threadIdx.x, lane = tid & 63, wid = tid >> 6;

    __shared__ alignas(16) float xs[Ee];
    __shared__ float4 tred[4][64];
    __shared__ float cred[4];
    __shared__ float c_sh;

    // Xsum: fixed 32 independent loads
    {
        const float* P = ws + P1_OFF + (size_t)b * BPB * Ee + tid;
        float a0 = 0.f, a1 = 0.f, a2 = 0.f, a3 = 0.f;
#pragma unroll
        for (int q = 0; q < BPB; q += 4) {
            a0 += P[(size_t)(q+0) * Ee];
            a1 += P[(size_t)(q+1) * Ee];
            a2 += P[(size_t)(q+2) * Ee];
            a3 += P[(size_t)(q+3) * Ee];
        }
        xs[tid] = (a0 + a1) + (a2 + a3);
    }
    __syncthreads();

    // t: wave wid covers ep in [wid*64, wid*64+64); lane owns e-quad
    {
        const float4* M4 = (const float4*)(ws + M_OFF);
        float4 tacc = {0.f, 0.f, 0.f, 0.f};
#pragma unroll 16
        for (int q = 0; q < 64; ++q) {
            const int ep = wid * 64 + q;
            const float s = xs[ep];
            const float4 m4 = M4[(size_t)ep * E4 + lane];
            tacc.x += s * m4.x; tacc.y += s * m4.y;
            tacc.z += s * m4.z; tacc.w += s * m4.w;
        }
        tred[wid][lane] = tacc;
    }
    {
        float p = xs[tid] * ws[KV_OFF + tid];
#pragma unroll
        for (int m = 32; m; m >>= 1) p += __shfl_xor(p, m, 64);
        if (lane == 0) cred[wid] = p;
    }
    __syncthreads();
    if (tid == 0) c_sh = cred[0] + cred[1] + cred[2] + cred[3] + (float)len * ws[BETA_OFF];
    float4 tv;
    {
        float4 a = tred[0][lane], b1 = tred[1][lane], c1 = tred[2][lane], d1 = tred[3][lane];
        const float4 bqk4 = ((const float4*)(ws + BQK_OFF))[lane];
        tv.x = a.x+b1.x+c1.x+d1.x + (float)len * bqk4.x;
        tv.y = a.y+b1.y+c1.y+d1.y + (float)len * bqk4.y;
        tv.z = a.z+b1.z+c1.z+d1.z + (float)len * bqk4.z;
        tv.w = a.w+b1.w+c1.w+d1.w + (float)len * bqk4.w;
    }
    __syncthreads();
    const float cb = c_sh;

    // stream 128 rows: fixed 32-iter unrolled, masked
    const float4* xb = (const float4*)(x + (size_t)b * Ll * Ee);
    float4 uacc = {0.f, 0.f, 0.f, 0.f};
    float wacc = 0.f;
#pragma unroll
    for (int rr = 0; rr < 32; ++rr) {
        const int r = r0 + wid + rr * 4;
        float4 xv = xb[(size_t)r * E4 + lane];         // padded rows valid memory
        float d = xv.x*tv.x + xv.y*tv.y + xv.z*tv.z + xv.w*tv.w;
#pragma unroll
        for (int m = 32; m; m >>= 1) d += __shfl_xor(d, m, 64);
        float w = (r < len) ? (d + cb) : 0.f;          // mask after reduce
        uacc.x += w*xv.x; uacc.y += w*xv.y; uacc.z += w*xv.z; uacc.w += w*xv.w;
        wacc += w;                                     // wave-uniform
    }
    __shared__ float4 part[256];
    __shared__ float cw[4];
    __shared__ alignas(16) float u_sh[Ee];
    __shared__ float w_sh;
    part[tid] = uacc;
    if (lane == 0) cw[wid] = wacc;
    __syncthreads();
    if (tid < 64) {
        float4 a = part[tid], b1 = part[64+tid], c1 = part[128+tid], d1 = part[192+tid];
        ((float4*)u_sh)[tid] = make_float4(a.x+b1.x+c1.x+d1.x, a.y+b1.y+c1.y+d1.y,
                                           a.z+b1.z+c1.z+d1.z, a.w+b1.w+c1.w+d1.w);
    }
    if (tid == 0) w_sh = cw[0] + cw[1] + cw[2] + cw[3];
    __syncthreads();

    // out[b,:] += (Wv . u_i + bv * w_i) / L
    const float4* wrow = (const float4*)(Wv + (size_t)tid * Ee);
    const float4* u4   = (const float4*)u_sh;
    float acc = 0.f;
#pragma unroll 8
    for (int q = 0; q < E4; ++q) {
        float4 w = wrow[q]; float4 v = u4[q];
        acc += w.x*v.x + w.y*v.y + w.z*v.z + w.w*v.w;
    }
    atomicAdd(out + b * Ee + tid, (acc + bv[tid] * w_sh) * (1.0f / (float)Ll));
}

extern "C" void kernel_launch(void* const* d_in, const int* in_sizes, int n_in,
                              void* d_out, int out_size, void* d_ws, size_t ws_size,
                              hipStream_t stream) {
    const float* x       = (const float*)d_in[0];
    const int*   lengths = (const int*)d_in[1];
    const float* Wq      = (const float*)d_in[2];
    const float* bq      = (const float*)d_in[3];
    const float* Wk      = (const float*)d_in[4];
    const float* bk      = (const float*)d_in[5];
    const float* Wv      = (const float*)d_in[6];
    const float* bv      = (const float*)d_in[7];
    float* out = (float*)d_out;
    float* ws  = (float*)d_ws;

    kPrep<<<Bb * BPB + Ee, 256, 0, stream>>>(x, lengths, Wq, bq, Wk, bk, ws, out);
    kMain<<<dim3(CBP, Bb), 256, 0, stream>>>(x, lengths, ws, Wv, bv, out);
}